// Round 4
// baseline (353.537 us; speedup 1.0000x reference)
//
#include <hip/hip_runtime.h>

#define IN_FEAT 4096
#define OUT_FEAT 4096
#define RANK 64
#define NROWS 16384
#define TM 32              // rows per block
#define KC 256             // K-chunk staged in LDS for wA'
#define WA_STRIDE 264      // wAsT inner stride (f16): 256 + 8 pad (528B, 16B-aligned)
#define XP_STRIDE 72       // xp / xp_part inner stride

typedef _Float16 half_t;
typedef _Float16 f16x4 __attribute__((ext_vector_type(4)));
typedef _Float16 f16x8 __attribute__((ext_vector_type(8)));
typedef float f32x4 __attribute__((ext_vector_type(4)));

// 2:4 soft-threshold one aligned group of 4, scale, cast to f16 (RNE).
// t = 2nd-smallest of the 4 |w| (== 3rd largest); out = sign(w)*relu(|w|-t)*s.
__device__ __forceinline__ f16x4 thr4(float4 v, float s) {
    float a0 = fabsf(v.x), a1 = fabsf(v.y), a2 = fabsf(v.z), a3 = fabsf(v.w);
    float lo1 = fminf(a0, a1), hi1 = fmaxf(a0, a1);
    float lo2 = fminf(a2, a3), hi2 = fmaxf(a2, a3);
    float t = fminf(fmaxf(lo1, lo2), fminf(hi1, hi2));
    f16x4 r;
    r[0] = (half_t)(copysignf(fmaxf(a0 - t, 0.0f), v.x) * s);
    r[1] = (half_t)(copysignf(fmaxf(a1 - t, 0.0f), v.y) * s);
    r[2] = (half_t)(copysignf(fmaxf(a2 - t, 0.0f), v.z) * s);
    r[3] = (half_t)(copysignf(fmaxf(a3 - t, 0.0f), v.w) * s);
    return r;
}

// Fully fused, ZERO-workspace kernel.
// Block: TM=32 rows, 4 waves. wave w: stripe=w&1 (16-row half), ks=w>>1
// (K-half in phase 1 / col-half in phase 2).
__global__ __launch_bounds__(256) void fused_kernel(
    const float* __restrict__ x, const float* __restrict__ wA,
    const float* __restrict__ wB, const float* __restrict__ bias,
    const float* __restrict__ scaleA, const float* __restrict__ scaleB,
    float* __restrict__ out)
{
    __shared__ __align__(16) half_t wAsT[RANK][WA_STRIDE];   // 33.8 KB: wA' chunk, [col][k]
    __shared__ float xp_part[2][TM][XP_STRIDE];              // 18.4 KB
    __shared__ __align__(16) half_t xp[TM][XP_STRIDE];       // 4.6 KB

    int tid  = threadIdx.x;
    int wave = tid >> 6;
    int lane = tid & 63;
    int l16  = lane & 15;
    int g    = lane >> 4;
    int rowbase = blockIdx.x * TM;
    int stripe  = wave & 1;
    int ks      = wave >> 1;

    float sA = scaleA[0];
    float sB = scaleB[0];

    // ---------------- Phase 1: xp = f16(x_tile) @ wA'  ----------------------
    const float* xrow = x + (size_t)(rowbase + stripe * 16 + l16) * IN_FEAT;
    f32x4 acc[4] = {f32x4{0,0,0,0}, f32x4{0,0,0,0}, f32x4{0,0,0,0}, f32x4{0,0,0,0}};

    for (int chunk = 0; chunk < IN_FEAT / KC; ++chunk) {     // 16 chunks
        int k0 = chunk * KC;

        // --- stage sparse wA' rows k0..k0+255 into wAsT[col][kloc], transposed
        // 512 patches of 8k x 4c; 2 per thread.
#pragma unroll
        for (int pp = 0; pp < 2; ++pp) {
            int p = tid + pp * 256;
            int q = p & 15;            // col group: cols 4q..4q+3
            int r = p >> 4;            // k-run: kloc 8r..8r+7
            f16x8 vc0, vc1, vc2, vc3;
#pragma unroll
            for (int i = 0; i < 8; ++i) {
                float4 v = *(const float4*)(wA + (size_t)(k0 + 8 * r + i) * RANK + 4 * q);
                f16x4 h = thr4(v, sA);
                vc0[i] = h[0]; vc1[i] = h[1]; vc2[i] = h[2]; vc3[i] = h[3];
            }
            *(f16x8*)&wAsT[4 * q + 0][8 * r] = vc0;
            *(f16x8*)&wAsT[4 * q + 1][8 * r] = vc1;
            *(f16x8*)&wAsT[4 * q + 2][8 * r] = vc2;
            *(f16x8*)&wAsT[4 * q + 3][8 * r] = vc3;
        }
        __syncthreads();

        // --- MFMA over this chunk; wave's K-half is kloc in [ks*128, ks*128+128)
#pragma unroll
        for (int it = 0; it < 4; ++it) {
            int kloc = ks * 128 + it * 32;
            float4 xa = *(const float4*)(xrow + k0 + kloc + 8 * g);
            float4 xb = *(const float4*)(xrow + k0 + kloc + 8 * g + 4);
            f16x8 a;
            a[0] = (half_t)xa.x; a[1] = (half_t)xa.y; a[2] = (half_t)xa.z; a[3] = (half_t)xa.w;
            a[4] = (half_t)xb.x; a[5] = (half_t)xb.y; a[6] = (half_t)xb.z; a[7] = (half_t)xb.w;
#pragma unroll
            for (int f = 0; f < 4; ++f) {
                f16x8 b = *(const f16x8*)&wAsT[16 * f + l16][kloc + 8 * g];
                acc[f] = __builtin_amdgcn_mfma_f32_16x16x32_f16(a, b, acc[f], 0, 0, 0);
            }
        }
        __syncthreads();   // before next chunk's staging overwrites wAsT
    }

    // C/D: col = lane&15, row = 4*(lane>>4)+reg
#pragma unroll
    for (int f = 0; f < 4; ++f)
#pragma unroll
        for (int r = 0; r < 4; ++r)
            xp_part[ks][stripe * 16 + 4 * g + r][16 * f + l16] = acc[f][r];
    __syncthreads();

    // reduce the two K-halves in f32, cast to f16 (ref: f32 x_proj -> f16 operand)
#pragma unroll
    for (int i = 0; i < (TM * RANK) / 256; ++i) {            // 8 iters
        int e = i * 256 + tid;
        int r = e >> 6, c = e & 63;
        xp[r][c] = (half_t)(xp_part[0][r][c] + xp_part[1][r][c]);
    }
    __syncthreads();

    // ---------------- Phase 2: out = xp @ wB'^T + bias ----------------------
    // wB' fragments are built on the fly: the k-run lies along rank, i.e. along
    // the 2:4 group axis, so each lane thresholds its own 2 groups in-register.
    {
        const half_t* xprow = &xp[stripe * 16 + l16][0];
        f16x8 a0 = *(const f16x8*)(xprow + 8 * g);           // k = 8g..8g+7
        f16x8 a1 = *(const f16x8*)(xprow + 32 + 8 * g);      // k = 32+8g..

        int cb0 = ks * (OUT_FEAT / 2);
        for (int cb = cb0; cb < cb0 + OUT_FEAT / 2; cb += 16) {
            int col = cb + l16;
            const float* wp = wB + (size_t)col * RANK;
            float4 w00 = *(const float4*)(wp + 8 * g);
            float4 w01 = *(const float4*)(wp + 8 * g + 4);
            float4 w10 = *(const float4*)(wp + 32 + 8 * g);
            float4 w11 = *(const float4*)(wp + 32 + 8 * g + 4);
            f16x4 b00 = thr4(w00, sB), b01 = thr4(w01, sB);
            f16x4 b10 = thr4(w10, sB), b11 = thr4(w11, sB);
            f16x8 b0, b1;
            b0[0]=b00[0]; b0[1]=b00[1]; b0[2]=b00[2]; b0[3]=b00[3];
            b0[4]=b01[0]; b0[5]=b01[1]; b0[6]=b01[2]; b0[7]=b01[3];
            b1[0]=b10[0]; b1[1]=b10[1]; b1[2]=b10[2]; b1[3]=b10[3];
            b1[4]=b11[0]; b1[5]=b11[1]; b1[6]=b11[2]; b1[7]=b11[3];

            f32x4 acc2 = {0, 0, 0, 0};
            acc2 = __builtin_amdgcn_mfma_f32_16x16x32_f16(a0, b0, acc2, 0, 0, 0);
            acc2 = __builtin_amdgcn_mfma_f32_16x16x32_f16(a1, b1, acc2, 0, 0, 0);
            float bv = bias[col];
#pragma unroll
            for (int r = 0; r < 4; ++r)
                out[(size_t)(rowbase + stripe * 16 + 4 * g + r) * OUT_FEAT + col] = acc2[r] + bv;
        }
    }
}

extern "C" void kernel_launch(void* const* d_in, const int* in_sizes, int n_in,
                              void* d_out, int out_size, void* d_ws, size_t ws_size,
                              hipStream_t stream) {
    const float* x      = (const float*)d_in[0];
    const float* wA     = (const float*)d_in[1];
    const float* wB     = (const float*)d_in[2];
    const float* bias   = (const float*)d_in[3];
    const float* scaleA = (const float*)d_in[4];
    const float* scaleB = (const float*)d_in[5];
    float* out = (float*)d_out;

    fused_kernel<<<NROWS / TM, 256, 0, stream>>>(x, wA, wB, bias, scaleA, scaleB, out);
}

// Round 6
// 261.847 us; speedup vs baseline: 1.3502x; 1.3502x over previous
//
#include <hip/hip_runtime.h>
#include <hip/hip_cooperative_groups.h>

namespace cg = cooperative_groups;

#define IN_FEAT 4096
#define OUT_FEAT 4096
#define RANK 64
#define NROWS 16384
#define TM 32              // rows per block
#define KC 256             // K-chunk staged in LDS (fallback kernel)
#define WA_STRIDE 264
#define XP_STRIDE 72

typedef _Float16 half_t;
typedef _Float16 f16x4 __attribute__((ext_vector_type(4)));
typedef _Float16 f16x8 __attribute__((ext_vector_type(8)));
typedef float f32x4 __attribute__((ext_vector_type(4)));

// 2:4 soft-threshold one aligned group of 4, scale, cast to f16 (RNE).
__device__ __forceinline__ f16x4 thr4(float4 v, float s) {
    float a0 = fabsf(v.x), a1 = fabsf(v.y), a2 = fabsf(v.z), a3 = fabsf(v.w);
    float lo1 = fminf(a0, a1), hi1 = fmaxf(a0, a1);
    float lo2 = fminf(a2, a3), hi2 = fmaxf(a2, a3);
    float t = fminf(fmaxf(lo1, lo2), fminf(hi1, hi2));  // 2nd-smallest = 3rd-largest
    f16x4 r;
    r[0] = (half_t)(copysignf(fmaxf(a0 - t, 0.0f), v.x) * s);
    r[1] = (half_t)(copysignf(fmaxf(a1 - t, 0.0f), v.y) * s);
    r[2] = (half_t)(copysignf(fmaxf(a2 - t, 0.0f), v.z) * s);
    r[3] = (half_t)(copysignf(fmaxf(a3 - t, 0.0f), v.w) * s);
    return r;
}

// ================= cooperative single-launch kernel =========================
// grid = 512 blocks x 256 threads, 2 blocks/CU co-resident (big margin).
// Phase 0: weight prep -> ws (1 MB). grid.sync. Phase A: 32-row G1 tile (xp in
// LDS). Phase B: G2 row-tile x all cols, prepped wBh from L2.
__global__ __launch_bounds__(256, 2) void coop_kernel(
    const float* __restrict__ x, const float* __restrict__ wA,
    const float* __restrict__ wB, const float* __restrict__ bias,
    const float* __restrict__ scaleA, const float* __restrict__ scaleB,
    float* __restrict__ out, half_t* __restrict__ wAT, half_t* __restrict__ wBh)
{
    __shared__ float xp_part[2][TM][XP_STRIDE];            // 18.4 KB
    __shared__ __align__(16) half_t xp[TM][XP_STRIDE];     // 4.6 KB

    int tid = threadIdx.x;
    int bid = blockIdx.x;

    // ---- Phase 0: prep. 512*256 = 131072 threads == 131072 groups ----------
    {
        int id = bid * 256 + tid;
        bool isB = id >= 65536;
        int gid = id & 65535;
        int row = gid >> 4;                    // 0..4095
        int gq  = gid & 15;                    // group-of-4 along rank
        const float* src = (isB ? wB : wA) + (size_t)row * RANK + gq * 4;
        float s = isB ? scaleB[0] : scaleA[0];
        f16x4 h = thr4(*(const float4*)src, s);
        if (!isB) {
            int c = gq * 4;
            wAT[(size_t)(c + 0) * IN_FEAT + row] = h[0];
            wAT[(size_t)(c + 1) * IN_FEAT + row] = h[1];
            wAT[(size_t)(c + 2) * IN_FEAT + row] = h[2];
            wAT[(size_t)(c + 3) * IN_FEAT + row] = h[3];
        } else {
            *(f16x4*)(wBh + (size_t)row * RANK + gq * 4) = h;
        }
    }
    cg::this_grid().sync();

    int wave = tid >> 6;
    int lane = tid & 63;
    int l16  = lane & 15;
    int g    = lane >> 4;
    int rowbase = bid * TM;
    int stripe  = wave & 1;                    // 16-row half
    int ks      = wave >> 1;                   // K-half (A) / col-half (B)

    // ---- Phase A: xp = f16(x_tile) @ wA' ; B-frags straight from L2 --------
    {
        const float* xrow = x + (size_t)(rowbase + stripe * 16 + l16) * IN_FEAT;
        int kbeg = ks * (IN_FEAT / 2);
        f32x4 acc[4] = {f32x4{0,0,0,0}, f32x4{0,0,0,0}, f32x4{0,0,0,0}, f32x4{0,0,0,0}};

        for (int k0 = kbeg; k0 < kbeg + IN_FEAT / 2; k0 += 32) {
            float4 xa = *(const float4*)(xrow + k0 + 8 * g);
            float4 xb = *(const float4*)(xrow + k0 + 8 * g + 4);
            f16x8 a;
            a[0] = (half_t)xa.x; a[1] = (half_t)xa.y; a[2] = (half_t)xa.z; a[3] = (half_t)xa.w;
            a[4] = (half_t)xb.x; a[5] = (half_t)xb.y; a[6] = (half_t)xb.z; a[7] = (half_t)xb.w;
#pragma unroll
            for (int f = 0; f < 4; ++f) {
                f16x8 b = *(const f16x8*)(wAT + (size_t)(16 * f + l16) * IN_FEAT + k0 + 8 * g);
                acc[f] = __builtin_amdgcn_mfma_f32_16x16x32_f16(a, b, acc[f], 0, 0, 0);
            }
        }
        // C/D: col = lane&15, row = 4*(lane>>4)+reg
#pragma unroll
        for (int f = 0; f < 4; ++f)
#pragma unroll
            for (int r = 0; r < 4; ++r)
                xp_part[ks][stripe * 16 + 4 * g + r][16 * f + l16] = acc[f][r];
    }
    __syncthreads();

#pragma unroll
    for (int i = 0; i < (TM * RANK) / 256; ++i) {          // 8 iters
        int e = i * 256 + tid;
        int r = e >> 6, c = e & 63;
        xp[r][c] = (half_t)(xp_part[0][r][c] + xp_part[1][r][c]);  // full-K f32 -> f16
    }
    __syncthreads();

    // ---- Phase B: out = xp @ wB'^T + bias ----------------------------------
    {
        const half_t* xprow = &xp[stripe * 16 + l16][0];
        f16x8 a0 = *(const f16x8*)(xprow + 8 * g);
        f16x8 a1 = *(const f16x8*)(xprow + 32 + 8 * g);

        int cb0 = ks * (OUT_FEAT / 2);
        for (int cb = cb0; cb < cb0 + OUT_FEAT / 2; cb += 64) {
#pragma unroll
            for (int f = 0; f < 4; ++f) {
                int col = cb + 16 * f + l16;
                const half_t* wp = wBh + (size_t)col * RANK;   // B[k][col] = wB'[col][k]
                f16x8 b0 = *(const f16x8*)(wp + 8 * g);
                f16x8 b1 = *(const f16x8*)(wp + 32 + 8 * g);
                f32x4 acc2 = {0, 0, 0, 0};
                acc2 = __builtin_amdgcn_mfma_f32_16x16x32_f16(a0, b0, acc2, 0, 0, 0);
                acc2 = __builtin_amdgcn_mfma_f32_16x16x32_f16(a1, b1, acc2, 0, 0, 0);
                float bv = bias[col];
#pragma unroll
                for (int r = 0; r < 4; ++r)
                    out[(size_t)(rowbase + stripe * 16 + 4 * g + r) * OUT_FEAT + col] = acc2[r] + bv;
            }
        }
    }
}

// ===================== fallback: zero-ws fused (round-4, passing) ===========
__global__ __launch_bounds__(256) void fused_kernel(
    const float* __restrict__ x, const float* __restrict__ wA,
    const float* __restrict__ wB, const float* __restrict__ bias,
    const float* __restrict__ scaleA, const float* __restrict__ scaleB,
    float* __restrict__ out)
{
    __shared__ __align__(16) half_t wAsT[RANK][WA_STRIDE];
    __shared__ float xp_part[2][TM][XP_STRIDE];
    __shared__ __align__(16) half_t xp[TM][XP_STRIDE];

    int tid  = threadIdx.x;
    int wave = tid >> 6;
    int lane = tid & 63;
    int l16  = lane & 15;
    int g    = lane >> 4;
    int rowbase = blockIdx.x * TM;
    int stripe  = wave & 1;
    int ks      = wave >> 1;

    float sA = scaleA[0];
    float sB = scaleB[0];

    const float* xrow = x + (size_t)(rowbase + stripe * 16 + l16) * IN_FEAT;
    f32x4 acc[4] = {f32x4{0,0,0,0}, f32x4{0,0,0,0}, f32x4{0,0,0,0}, f32x4{0,0,0,0}};

    for (int chunk = 0; chunk < IN_FEAT / KC; ++chunk) {
        int k0 = chunk * KC;
#pragma unroll
        for (int pp = 0; pp < 2; ++pp) {
            int p = tid + pp * 256;
            int q = p & 15;
            int r = p >> 4;
            f16x8 vc0, vc1, vc2, vc3;
#pragma unroll
            for (int i = 0; i < 8; ++i) {
                float4 v = *(const float4*)(wA + (size_t)(k0 + 8 * r + i) * RANK + 4 * q);
                f16x4 h = thr4(v, sA);
                vc0[i] = h[0]; vc1[i] = h[1]; vc2[i] = h[2]; vc3[i] = h[3];
            }
            *(f16x8*)&wAsT[4 * q + 0][8 * r] = vc0;
            *(f16x8*)&wAsT[4 * q + 1][8 * r] = vc1;
            *(f16x8*)&wAsT[4 * q + 2][8 * r] = vc2;
            *(f16x8*)&wAsT[4 * q + 3][8 * r] = vc3;
        }
        __syncthreads();

#pragma unroll
        for (int it = 0; it < 4; ++it) {
            int kloc = ks * 128 + it * 32;
            float4 xa = *(const float4*)(xrow + k0 + kloc + 8 * g);
            float4 xb = *(const float4*)(xrow + k0 + kloc + 8 * g + 4);
            f16x8 a;
            a[0] = (half_t)xa.x; a[1] = (half_t)xa.y; a[2] = (half_t)xa.z; a[3] = (half_t)xa.w;
            a[4] = (half_t)xb.x; a[5] = (half_t)xb.y; a[6] = (half_t)xb.z; a[7] = (half_t)xb.w;
#pragma unroll
            for (int f = 0; f < 4; ++f) {
                f16x8 b = *(const f16x8*)&wAsT[16 * f + l16][kloc + 8 * g];
                acc[f] = __builtin_amdgcn_mfma_f32_16x16x32_f16(a, b, acc[f], 0, 0, 0);
            }
        }
        __syncthreads();
    }

#pragma unroll
    for (int f = 0; f < 4; ++f)
#pragma unroll
        for (int r = 0; r < 4; ++r)
            xp_part[ks][stripe * 16 + 4 * g + r][16 * f + l16] = acc[f][r];
    __syncthreads();

#pragma unroll
    for (int i = 0; i < (TM * RANK) / 256; ++i) {
        int e = i * 256 + tid;
        int r = e >> 6, c = e & 63;
        xp[r][c] = (half_t)(xp_part[0][r][c] + xp_part[1][r][c]);
    }
    __syncthreads();

    {
        const half_t* xprow = &xp[stripe * 16 + l16][0];
        f16x8 a0 = *(const f16x8*)(xprow + 8 * g);
        f16x8 a1 = *(const f16x8*)(xprow + 32 + 8 * g);

        int cb0 = ks * (OUT_FEAT / 2);
        for (int cb = cb0; cb < cb0 + OUT_FEAT / 2; cb += 16) {
            int col = cb + l16;
            const float* wp = wB + (size_t)col * RANK;
            float4 w00 = *(const float4*)(wp + 8 * g);
            float4 w01 = *(const float4*)(wp + 8 * g + 4);
            float4 w10 = *(const float4*)(wp + 32 + 8 * g);
            float4 w11 = *(const float4*)(wp + 32 + 8 * g + 4);
            f16x4 b00 = thr4(w00, sB), b01 = thr4(w01, sB);
            f16x4 b10 = thr4(w10, sB), b11 = thr4(w11, sB);
            f16x8 b0, b1;
            b0[0]=b00[0]; b0[1]=b00[1]; b0[2]=b00[2]; b0[3]=b00[3];
            b0[4]=b01[0]; b0[5]=b01[1]; b0[6]=b01[2]; b0[7]=b01[3];
            b1[0]=b10[0]; b1[1]=b10[1]; b1[2]=b10[2]; b1[3]=b10[3];
            b1[4]=b11[0]; b1[5]=b11[1]; b1[6]=b11[2]; b1[7]=b11[3];

            f32x4 acc2 = {0, 0, 0, 0};
            acc2 = __builtin_amdgcn_mfma_f32_16x16x32_f16(a0, b0, acc2, 0, 0, 0);
            acc2 = __builtin_amdgcn_mfma_f32_16x16x32_f16(a1, b1, acc2, 0, 0, 0);
            float bv = bias[col];
#pragma unroll
            for (int r = 0; r < 4; ++r)
                out[(size_t)(rowbase + stripe * 16 + 4 * g + r) * OUT_FEAT + col] = acc2[r] + bv;
        }
    }
}

extern "C" void kernel_launch(void* const* d_in, const int* in_sizes, int n_in,
                              void* d_out, int out_size, void* d_ws, size_t ws_size,
                              hipStream_t stream) {
    const float* x      = (const float*)d_in[0];
    const float* wA     = (const float*)d_in[1];
    const float* wB     = (const float*)d_in[2];
    const float* bias   = (const float*)d_in[3];
    const float* scaleA = (const float*)d_in[4];
    const float* scaleB = (const float*)d_in[5];
    float* out = (float*)d_out;

    const size_t WS_NEED = (size_t)RANK * IN_FEAT * 2      // wAT 512 KB
                         + (size_t)OUT_FEAT * RANK * 2;    // wBh 512 KB

    if (ws_size >= WS_NEED && d_ws != nullptr) {
        half_t* wAT = (half_t*)d_ws;
        half_t* wBh = wAT + (size_t)RANK * IN_FEAT;
        void* args[] = {(void*)&x, (void*)&wA, (void*)&wB, (void*)&bias,
                        (void*)&scaleA, (void*)&scaleB, (void*)&out,
                        (void*)&wAT, (void*)&wBh};
        hipLaunchCooperativeKernel((void*)coop_kernel, dim3(NROWS / TM), dim3(256),
                                   args, 0, stream);
    } else {
        fused_kernel<<<NROWS / TM, 256, 0, stream>>>(x, wA, wB, bias, scaleA, scaleB, out);
    }
}

// Round 7
// 239.502 us; speedup vs baseline: 1.4761x; 1.0933x over previous
//
#include <hip/hip_runtime.h>
#include <hip/hip_cooperative_groups.h>

namespace cg = cooperative_groups;

#define IN_FEAT 4096
#define OUT_FEAT 4096
#define RANK 64
#define NROWS 16384
#define TM 32              // rows per block
#define BT 512             // threads per block (8 waves)
#define KC 256             // K-chunk staged in LDS (fallback kernel)
#define WA_STRIDE 264
#define XP_STRIDE 72
#define PART_STRIDE 68     // f32 partial stride: 4g*68 % 32banks -> 2-way (free)

typedef _Float16 half_t;
typedef _Float16 f16x4 __attribute__((ext_vector_type(4)));
typedef _Float16 f16x8 __attribute__((ext_vector_type(8)));
typedef float f32x4 __attribute__((ext_vector_type(4)));

// 2:4 soft-threshold one aligned group of 4, scale, cast to f16 (RNE).
__device__ __forceinline__ f16x4 thr4(float4 v, float s) {
    float a0 = fabsf(v.x), a1 = fabsf(v.y), a2 = fabsf(v.z), a3 = fabsf(v.w);
    float lo1 = fminf(a0, a1), hi1 = fmaxf(a0, a1);
    float lo2 = fminf(a2, a3), hi2 = fmaxf(a2, a3);
    float t = fminf(fmaxf(lo1, lo2), fminf(hi1, hi2));  // 2nd-smallest = 3rd-largest
    f16x4 r;
    r[0] = (half_t)(copysignf(fmaxf(a0 - t, 0.0f), v.x) * s);
    r[1] = (half_t)(copysignf(fmaxf(a1 - t, 0.0f), v.y) * s);
    r[2] = (half_t)(copysignf(fmaxf(a2 - t, 0.0f), v.z) * s);
    r[3] = (half_t)(copysignf(fmaxf(a3 - t, 0.0f), v.w) * s);
    return r;
}

// ================= cooperative single-launch kernel =========================
// grid = 512 blocks x 512 threads (8 waves), 2 blocks/CU -> 16 waves/CU.
// Phase 0: weight prep -> ws. grid.sync. Phase A: G1 (K quartered across wave
// pairs). Phase B: G2 (cols quartered across wave pairs).
__global__ __launch_bounds__(512) void coop_kernel(
    const float* __restrict__ x, const float* __restrict__ wA,
    const float* __restrict__ wB, const float* __restrict__ bias,
    const float* __restrict__ scaleA, const float* __restrict__ scaleB,
    float* __restrict__ out, half_t* __restrict__ wAT, half_t* __restrict__ wBh)
{
    __shared__ float xp_part[4][TM][PART_STRIDE];          // 34.8 KB
    __shared__ __align__(16) half_t xp[TM][XP_STRIDE];     // 4.6 KB

    int tid = threadIdx.x;
    int bid = blockIdx.x;

    // ---- Phase 0: prep. 131072 group-tasks over 262144 threads -------------
    {
        int id = bid * BT + tid;
        if (id < 131072) {
            bool isB = id >= 65536;
            int gid = id & 65535;
            int row = gid >> 4;                    // 0..4095
            int gq  = gid & 15;                    // group-of-4 along rank
            const float* src = (isB ? wB : wA) + (size_t)row * RANK + gq * 4;
            float s = isB ? scaleB[0] : scaleA[0];
            f16x4 h = thr4(*(const float4*)src, s);
            if (!isB) {
                int c = gq * 4;
                wAT[(size_t)(c + 0) * IN_FEAT + row] = h[0];
                wAT[(size_t)(c + 1) * IN_FEAT + row] = h[1];
                wAT[(size_t)(c + 2) * IN_FEAT + row] = h[2];
                wAT[(size_t)(c + 3) * IN_FEAT + row] = h[3];
            } else {
                *(f16x4*)(wBh + (size_t)row * RANK + gq * 4) = h;
            }
        }
    }
    cg::this_grid().sync();

    int wave = tid >> 6;                           // 0..7
    int lane = tid & 63;
    int l16  = lane & 15;
    int g    = lane >> 4;
    int rowbase = bid * TM;
    int stripe  = wave & 1;                        // 16-row half
    int ks      = wave >> 1;                       // K-quarter (A) / col-quarter (B)

    // ---- Phase A: xp = f16(x_tile) @ wA' ; B-frags straight from L2 --------
    {
        const float* xrow = x + (size_t)(rowbase + stripe * 16 + l16) * IN_FEAT;
        int kbeg = ks * (IN_FEAT / 4);
        f32x4 acc[4] = {f32x4{0,0,0,0}, f32x4{0,0,0,0}, f32x4{0,0,0,0}, f32x4{0,0,0,0}};

#pragma unroll 2
        for (int k0 = kbeg; k0 < kbeg + IN_FEAT / 4; k0 += 32) {
            float4 xa = *(const float4*)(xrow + k0 + 8 * g);
            float4 xb = *(const float4*)(xrow + k0 + 8 * g + 4);
            f16x8 a;
            a[0] = (half_t)xa.x; a[1] = (half_t)xa.y; a[2] = (half_t)xa.z; a[3] = (half_t)xa.w;
            a[4] = (half_t)xb.x; a[5] = (half_t)xb.y; a[6] = (half_t)xb.z; a[7] = (half_t)xb.w;
#pragma unroll
            for (int f = 0; f < 4; ++f) {
                f16x8 b = *(const f16x8*)(wAT + (size_t)(16 * f + l16) * IN_FEAT + k0 + 8 * g);
                acc[f] = __builtin_amdgcn_mfma_f32_16x16x32_f16(a, b, acc[f], 0, 0, 0);
            }
        }
        // C/D: col = lane&15, row = 4*(lane>>4)+reg
#pragma unroll
        for (int f = 0; f < 4; ++f)
#pragma unroll
            for (int r = 0; r < 4; ++r)
                xp_part[ks][stripe * 16 + 4 * g + r][16 * f + l16] = acc[f][r];
    }
    __syncthreads();

#pragma unroll
    for (int i = 0; i < (TM * RANK) / BT; ++i) {           // 4 iters
        int e = i * BT + tid;
        int r = e >> 6, c = e & 63;
        xp[r][c] = (half_t)((xp_part[0][r][c] + xp_part[1][r][c]) +
                            (xp_part[2][r][c] + xp_part[3][r][c]));  // full-K f32 -> f16
    }
    __syncthreads();

    // ---- Phase B: out = xp @ wB'^T + bias ----------------------------------
    {
        const half_t* xprow = &xp[stripe * 16 + l16][0];
        f16x8 a0 = *(const f16x8*)(xprow + 8 * g);
        f16x8 a1 = *(const f16x8*)(xprow + 32 + 8 * g);

        int cb0 = ks * (OUT_FEAT / 4);
        for (int cb = cb0; cb < cb0 + OUT_FEAT / 4; cb += 64) {
#pragma unroll
            for (int f = 0; f < 4; ++f) {
                int col = cb + 16 * f + l16;
                const half_t* wp = wBh + (size_t)col * RANK;   // B[k][col] = wB'[col][k]
                f16x8 b0 = *(const f16x8*)(wp + 8 * g);
                f16x8 b1 = *(const f16x8*)(wp + 32 + 8 * g);
                f32x4 acc2 = {0, 0, 0, 0};
                acc2 = __builtin_amdgcn_mfma_f32_16x16x32_f16(a0, b0, acc2, 0, 0, 0);
                acc2 = __builtin_amdgcn_mfma_f32_16x16x32_f16(a1, b1, acc2, 0, 0, 0);
                float bv = bias[col];
#pragma unroll
                for (int r = 0; r < 4; ++r)
                    __builtin_nontemporal_store(acc2[r] + bv,
                        &out[(size_t)(rowbase + stripe * 16 + 4 * g + r) * OUT_FEAT + col]);
            }
        }
    }
}

// ===================== fallback: zero-ws fused (round-4, passing) ===========
__global__ __launch_bounds__(256) void fused_kernel(
    const float* __restrict__ x, const float* __restrict__ wA,
    const float* __restrict__ wB, const float* __restrict__ bias,
    const float* __restrict__ scaleA, const float* __restrict__ scaleB,
    float* __restrict__ out)
{
    __shared__ __align__(16) half_t wAsT[RANK][WA_STRIDE];
    __shared__ float xp_part[2][TM][XP_STRIDE];
    __shared__ __align__(16) half_t xp[TM][XP_STRIDE];

    int tid  = threadIdx.x;
    int wave = tid >> 6;
    int lane = tid & 63;
    int l16  = lane & 15;
    int g    = lane >> 4;
    int rowbase = blockIdx.x * TM;
    int stripe  = wave & 1;
    int ks      = wave >> 1;

    float sA = scaleA[0];
    float sB = scaleB[0];

    const float* xrow = x + (size_t)(rowbase + stripe * 16 + l16) * IN_FEAT;
    f32x4 acc[4] = {f32x4{0,0,0,0}, f32x4{0,0,0,0}, f32x4{0,0,0,0}, f32x4{0,0,0,0}};

    for (int chunk = 0; chunk < IN_FEAT / KC; ++chunk) {
        int k0 = chunk * KC;
#pragma unroll
        for (int pp = 0; pp < 2; ++pp) {
            int p = tid + pp * 256;
            int q = p & 15;
            int r = p >> 4;
            f16x8 vc0, vc1, vc2, vc3;
#pragma unroll
            for (int i = 0; i < 8; ++i) {
                float4 v = *(const float4*)(wA + (size_t)(k0 + 8 * r + i) * RANK + 4 * q);
                f16x4 h = thr4(v, sA);
                vc0[i] = h[0]; vc1[i] = h[1]; vc2[i] = h[2]; vc3[i] = h[3];
            }
            *(f16x8*)&wAsT[4 * q + 0][8 * r] = vc0;
            *(f16x8*)&wAsT[4 * q + 1][8 * r] = vc1;
            *(f16x8*)&wAsT[4 * q + 2][8 * r] = vc2;
            *(f16x8*)&wAsT[4 * q + 3][8 * r] = vc3;
        }
        __syncthreads();

#pragma unroll
        for (int it = 0; it < 4; ++it) {
            int kloc = ks * 128 + it * 32;
            float4 xa = *(const float4*)(xrow + k0 + kloc + 8 * g);
            float4 xb = *(const float4*)(xrow + k0 + kloc + 8 * g + 4);
            f16x8 a;
            a[0] = (half_t)xa.x; a[1] = (half_t)xa.y; a[2] = (half_t)xa.z; a[3] = (half_t)xa.w;
            a[4] = (half_t)xb.x; a[5] = (half_t)xb.y; a[6] = (half_t)xb.z; a[7] = (half_t)xb.w;
#pragma unroll
            for (int f = 0; f < 4; ++f) {
                f16x8 b = *(const f16x8*)&wAsT[16 * f + l16][kloc + 8 * g];
                acc[f] = __builtin_amdgcn_mfma_f32_16x16x32_f16(a, b, acc[f], 0, 0, 0);
            }
        }
        __syncthreads();
    }

#pragma unroll
    for (int f = 0; f < 4; ++f)
#pragma unroll
        for (int r = 0; r < 4; ++r)
            xp_part[ks][stripe * 16 + 4 * g + r][16 * f + l16] = acc[f][r];
    __syncthreads();

#pragma unroll
    for (int i = 0; i < (TM * RANK) / 256; ++i) {
        int e = i * 256 + tid;
        int r = e >> 6, c = e & 63;
        xp[r][c] = (half_t)(xp_part[0][r][c] + xp_part[1][r][c]);
    }
    __syncthreads();

    {
        const half_t* xprow = &xp[stripe * 16 + l16][0];
        f16x8 a0 = *(const f16x8*)(xprow + 8 * g);
        f16x8 a1 = *(const f16x8*)(xprow + 32 + 8 * g);

        int cb0 = ks * (OUT_FEAT / 2);
        for (int cb = cb0; cb < cb0 + OUT_FEAT / 2; cb += 16) {
            int col = cb + l16;
            const float* wp = wB + (size_t)col * RANK;
            float4 w00 = *(const float4*)(wp + 8 * g);
            float4 w01 = *(const float4*)(wp + 8 * g + 4);
            float4 w10 = *(const float4*)(wp + 32 + 8 * g);
            float4 w11 = *(const float4*)(wp + 32 + 8 * g + 4);
            f16x4 b00 = thr4(w00, sB), b01 = thr4(w01, sB);
            f16x4 b10 = thr4(w10, sB), b11 = thr4(w11, sB);
            f16x8 b0, b1;
            b0[0]=b00[0]; b0[1]=b00[1]; b0[2]=b00[2]; b0[3]=b00[3];
            b0[4]=b01[0]; b0[5]=b01[1]; b0[6]=b01[2]; b0[7]=b01[3];
            b1[0]=b10[0]; b1[1]=b10[1]; b1[2]=b10[2]; b1[3]=b10[3];
            b1[4]=b11[0]; b1[5]=b11[1]; b1[6]=b11[2]; b1[7]=b11[3];

            f32x4 acc2 = {0, 0, 0, 0};
            acc2 = __builtin_amdgcn_mfma_f32_16x16x32_f16(a0, b0, acc2, 0, 0, 0);
            acc2 = __builtin_amdgcn_mfma_f32_16x16x32_f16(a1, b1, acc2, 0, 0, 0);
            float bv = bias[col];
#pragma unroll
            for (int r = 0; r < 4; ++r)
                out[(size_t)(rowbase + stripe * 16 + 4 * g + r) * OUT_FEAT + col] = acc2[r] + bv;
        }
    }
}

extern "C" void kernel_launch(void* const* d_in, const int* in_sizes, int n_in,
                              void* d_out, int out_size, void* d_ws, size_t ws_size,
                              hipStream_t stream) {
    const float* x      = (const float*)d_in[0];
    const float* wA     = (const float*)d_in[1];
    const float* wB     = (const float*)d_in[2];
    const float* bias   = (const float*)d_in[3];
    const float* scaleA = (const float*)d_in[4];
    const float* scaleB = (const float*)d_in[5];
    float* out = (float*)d_out;

    const size_t WS_NEED = (size_t)RANK * IN_FEAT * 2      // wAT 512 KB
                         + (size_t)OUT_FEAT * RANK * 2;    // wBh 512 KB

    if (ws_size >= WS_NEED && d_ws != nullptr) {
        half_t* wAT = (half_t*)d_ws;
        half_t* wBh = wAT + (size_t)RANK * IN_FEAT;
        void* args[] = {(void*)&x, (void*)&wA, (void*)&wB, (void*)&bias,
                        (void*)&scaleA, (void*)&scaleB, (void*)&out,
                        (void*)&wAT, (void*)&wBh};
        hipLaunchCooperativeKernel((void*)coop_kernel, dim3(NROWS / TM), dim3(BT),
                                   args, 0, stream);
    } else {
        fused_kernel<<<NROWS / TM, 256, 0, stream>>>(x, wA, wB, bias, scaleA, scaleB, out);
    }
}